// Round 1
// baseline (528.653 us; speedup 1.0000x reference)
//
#include <hip/hip_runtime.h>
#include <hip/hip_bf16.h>

#define S_LEN 2048
#define DMODEL 4096
#define NH 32
#define NKV 8
#define HD 128
#define NQKV 6144
#define ATT_SCALE 0.08838834764831845f  // 1/sqrt(128)

typedef __bf16 bf16x8 __attribute__((ext_vector_type(8)));
typedef float f32x4 __attribute__((ext_vector_type(4)));

// float -> bf16 bits, round-to-nearest-even
__device__ __forceinline__ unsigned short f2b(float f) {
  union { float f; unsigned u; } a; a.f = f;
  unsigned u = a.u;
  return (unsigned short)((u + 0x7FFFu + ((u >> 16) & 1u)) >> 16);
}

__device__ __forceinline__ void gload_lds16(const void* g, void* l) {
  __builtin_amdgcn_global_load_lds(
      (const __attribute__((address_space(1))) unsigned int*)g,
      (__attribute__((address_space(3))) unsigned int*)l, 16, 0, 0);
}

// ---------------- x fp32 -> bf16 ----------------
__global__ __launch_bounds__(256) void k_cvt_x(const float* __restrict__ x,
                                               unsigned short* __restrict__ xb) {
  int i = blockIdx.x * 256 + threadIdx.x;
  float4 v = ((const float4*)x)[i];
  ushort4 o;
  o.x = f2b(v.x); o.y = f2b(v.y); o.z = f2b(v.z); o.w = f2b(v.w);
  ((ushort4*)xb)[i] = o;
}

// ------------- W (K,N) fp32 -> Wt (N,K) bf16 -------------
__global__ __launch_bounds__(256) void k_transpose(const float* __restrict__ W,
                                                   unsigned short* __restrict__ Wt,
                                                   int K, int N) {
  __shared__ float tile[64][65];
  int k0 = blockIdx.x * 64, n0 = blockIdx.y * 64;
  int tx = threadIdx.x & 31, ty = threadIdx.x >> 5;
#pragma unroll
  for (int i = 0; i < 8; ++i) {
    int k = ty + i * 8;
    const float* src = W + (size_t)(k0 + k) * N + n0;
    tile[k][tx] = src[tx];
    tile[k][tx + 32] = src[tx + 32];
  }
  __syncthreads();
#pragma unroll
  for (int i = 0; i < 8; ++i) {
    int n = ty + i * 8;
    unsigned short* dst = Wt + (size_t)(n0 + n) * K + k0;
    dst[tx] = f2b(tile[tx][n]);
    dst[tx + 32] = f2b(tile[tx + 32][n]);
  }
}

// ------------- GEMM: C(MxN) fp32 = A(MxK) bf16 * Bt(NxK) bf16 -------------
// m97 structure: 128x128 tile, BK=32, 4 waves (2x2 of 64x64), global_load_lds w16
__global__ __launch_bounds__(256) void k_gemm_bt(const unsigned short* __restrict__ A,
                                                 const unsigned short* __restrict__ B,
                                                 float* __restrict__ C,
                                                 int M, int N, int K) {
  __shared__ __align__(16) unsigned short As[128 * 32];
  __shared__ __align__(16) unsigned short Bs[128 * 32];
  const int tid = threadIdx.x, wv = tid >> 6, l = tid & 63;
  const int m0 = blockIdx.x * 128, n0 = blockIdx.y * 128;
  const int wm = (wv >> 1) * 64, wn = (wv & 1) * 64;
  const int l15 = l & 15, l4 = l >> 4;
  f32x4 acc[4][4] = {};
  for (int k0 = 0; k0 < K; k0 += 32) {
    __syncthreads();
#pragma unroll
    for (int j = 0; j < 2; ++j) {
      int rbase = wv * 32 + j * 16;
      const unsigned short* ga = A + (size_t)(m0 + rbase + (l >> 2)) * K + k0 + (l & 3) * 8;
      gload_lds16(ga, &As[rbase * 32]);
      const unsigned short* gb = B + (size_t)(n0 + rbase + (l >> 2)) * K + k0 + (l & 3) * 8;
      gload_lds16(gb, &Bs[rbase * 32]);
    }
    __syncthreads();
    bf16x8 af[4], bfr[4];
#pragma unroll
    for (int i = 0; i < 4; ++i)
      af[i] = *(const bf16x8*)&As[(wm + i * 16 + l15) * 32 + l4 * 8];
#pragma unroll
    for (int i = 0; i < 4; ++i)
      bfr[i] = *(const bf16x8*)&Bs[(wn + i * 16 + l15) * 32 + l4 * 8];
#pragma unroll
    for (int i = 0; i < 4; ++i)
#pragma unroll
      for (int j = 0; j < 4; ++j)
        acc[i][j] = __builtin_amdgcn_mfma_f32_16x16x32_bf16(af[i], bfr[j], acc[i][j], 0, 0, 0);
  }
#pragma unroll
  for (int i = 0; i < 4; ++i)
#pragma unroll
    for (int j = 0; j < 4; ++j)
#pragma unroll
      for (int r = 0; r < 4; ++r) {
        int row = m0 + wm + i * 16 + l4 * 4 + r;
        int col = n0 + wn + j * 16 + l15;
        C[(size_t)row * N + col] = acc[i][j][r];
      }
}

// ------------- RoPE + int8 quantize (stored as bf16 ints) -------------
__global__ __launch_bounds__(256) void k_ropequant(const float* __restrict__ qkv,
                                                   const float* __restrict__ cost,
                                                   const float* __restrict__ sint,
                                                   unsigned short* __restrict__ q_int,
                                                   float* __restrict__ q_ds,
                                                   unsigned short* __restrict__ k_int,
                                                   float* __restrict__ k_ds,
                                                   unsigned short* __restrict__ v_bf) {
  int s = blockIdx.x;
  int wv = threadIdx.x >> 6, l = threadIdx.x & 63;
  int hh = blockIdx.y * 4 + wv;  // 0..47: [0,32) q, [32,40) k, [40,48) v
  const float* row = qkv + (size_t)s * NQKV;
  if (hh < NH + NKV) {
    int off = (hh < NH) ? hh * HD : DMODEL + (hh - NH) * HD;
    float t1 = row[off + l], t2 = row[off + 64 + l];
    float c1 = cost[s * HD + l],      sn1 = sint[s * HD + l];
    float c2 = cost[s * HD + 64 + l], sn2 = sint[s * HD + 64 + l];
    float o1 = t1 * c1 - t2 * sn1;   // d < 64 : t*c - t[d+64]*s
    float o2 = t2 * c2 + t1 * sn2;   // d >= 64: t*c + t[d-64]*s
    float amax = fmaxf(fabsf(o1), fabsf(o2));
#pragma unroll
    for (int m = 1; m < 64; m <<= 1) amax = fmaxf(amax, __shfl_xor(amax, m));
    amax = fmaxf(amax, 1e-5f);
    float scale = 127.0f / amax;          // quant scale
    float dscale = amax * (1.0f / 127.0f); // dequant scale
    float v1 = fminf(fmaxf(rintf(o1 * scale), -128.f), 127.f);
    float v2 = fminf(fmaxf(rintf(o2 * scale), -128.f), 127.f);
    if (hh < NH) {
      unsigned short* dst = q_int + ((size_t)s * NH + hh) * HD;
      dst[l] = f2b(v1); dst[l + 64] = f2b(v2);
      if (l == 0) q_ds[(size_t)s * NH + hh] = dscale;
    } else {
      int kh = hh - NH;
      unsigned short* dst = k_int + ((size_t)s * NKV + kh) * HD;
      dst[l] = f2b(v1); dst[l + 64] = f2b(v2);
      if (l == 0) k_ds[(size_t)s * NKV + kh] = dscale;
    }
  } else {
    int vh = hh - (NH + NKV);
    const float* src = row + DMODEL + NKV * HD + vh * HD;
    unsigned short* dst = v_bf + ((size_t)s * NKV + vh) * HD;
    dst[l] = f2b(src[l]);
    dst[l + 64] = f2b(src[l + 64]);
  }
}

// ------------- causal GQA flash attention -------------
// grid (S/64, NH); 4 waves x 16 q-rows; KV tile 64
__global__ __launch_bounds__(256) void k_attn(const unsigned short* __restrict__ q_int,
                                              const float* __restrict__ q_ds,
                                              const unsigned short* __restrict__ k_int,
                                              const float* __restrict__ k_ds,
                                              const unsigned short* __restrict__ v_bf,
                                              unsigned short* __restrict__ o_bf) {
  __shared__ __align__(16) unsigned short K_lds[64 * 128];   // XOR-swizzled rows
  __shared__ __align__(16) unsigned short Vt_lds[128 * 64];  // transposed, group-swizzled
  __shared__ __align__(16) unsigned short P_lds[4][16 * 72];
  __shared__ float ks_lds[64];
  const int qb = blockIdx.x, h = blockIdx.y, kvh = h >> 2;
  const int tid = threadIdx.x, wv = tid >> 6, l = tid & 63;
  const int l15 = l & 15, l4 = l >> 4;
  const int q0 = qb * 64;
  const int qrow_lo = q0 + wv * 16;
  const int crow = qrow_lo + l4 * 4;  // C-layout row base for this lane

  bf16x8 qf[4];
  {
    const unsigned short* qp = q_int + ((size_t)(qrow_lo + l15) * NH + h) * HD + l4 * 8;
#pragma unroll
    for (int kd = 0; kd < 4; ++kd) qf[kd] = *(const bf16x8*)(qp + kd * 32);
  }
  float qsS[4];
#pragma unroll
  for (int r = 0; r < 4; ++r) qsS[r] = ATT_SCALE * q_ds[(size_t)(crow + r) * NH + h];

  float m_run[4], l_run[4];
  f32x4 o_acc[8] = {};
#pragma unroll
  for (int r = 0; r < 4; ++r) { m_run[r] = -3.0e38f; l_run[r] = 0.f; }

  const int nkt = qb + 1;
  for (int kt = 0; kt < nkt; ++kt) {
    __syncthreads();
    // stage K tile [64 keys][128 d], byte ^= (key&7)<<4
#pragma unroll
    for (int j = 0; j < 4; ++j) {
      int idx = tid + j * 256;
      int key = idx >> 4;
      int d0 = (idx & 15) * 8;
      uint4 data = *(const uint4*)(k_int + ((size_t)(kt * 64 + key) * NKV + kvh) * HD + d0);
      int byte = key * 256 + d0 * 2;
      byte ^= (key & 7) << 4;
      *(uint4*)((char*)K_lds + byte) = data;
    }
    // stage V transposed: elem (d,key) -> d*64 + ((key>>3 ^ (d&7) ^ ((d>>3)&7))<<3) + (key&7)
#pragma unroll
    for (int j = 0; j < 4; ++j) {
      int idx = tid + j * 256;
      int key = idx >> 4;
      int d0 = (idx & 15) * 8;
      uint4 data = *(const uint4*)(v_bf + ((size_t)(kt * 64 + key) * NKV + kvh) * HD + d0);
      union { uint4 u; unsigned short s[8]; } td; td.u = data;
      int key3 = key >> 3, keylo = key & 7;
      int dg = (d0 >> 3) & 7;
#pragma unroll
      for (int e = 0; e < 8; ++e) {
        int d = d0 + e;
        int grp = key3 ^ e ^ dg;
        Vt_lds[d * 64 + (grp << 3) + keylo] = td.s[e];
      }
    }
    if (tid < 64) ks_lds[tid] = k_ds[(size_t)(kt * 64 + tid) * NKV + kvh];
    __syncthreads();

    // QK^T (exact int accumulate in fp32)
    f32x4 sacc[4] = {};
#pragma unroll
    for (int nt = 0; nt < 4; ++nt) {
      int key = nt * 16 + l15;
#pragma unroll
      for (int kd = 0; kd < 4; ++kd) {
        int byte = key * 256 + kd * 64 + l4 * 16;
        byte ^= (key & 7) << 4;
        bf16x8 kf = *(const bf16x8*)((const char*)K_lds + byte);
        sacc[nt] = __builtin_amdgcn_mfma_f32_16x16x32_bf16(qf[kd], kf, sacc[nt], 0, 0, 0);
      }
    }

    // scale + causal mask + online softmax
    float p[4][4];
    float tmax[4] = {-3.0e38f, -3.0e38f, -3.0e38f, -3.0e38f};
#pragma unroll
    for (int nt = 0; nt < 4; ++nt) {
      int keyg = kt * 64 + nt * 16 + l15;
      float ksd = ks_lds[nt * 16 + l15];
#pragma unroll
      for (int r = 0; r < 4; ++r) {
        float sc = sacc[nt][r] * (qsS[r] * ksd);
        sc = (keyg <= crow + r) ? sc : -3.0e38f;
        p[nt][r] = sc;
        tmax[r] = fmaxf(tmax[r], sc);
      }
    }
#pragma unroll
    for (int m = 1; m < 16; m <<= 1)
#pragma unroll
      for (int r = 0; r < 4; ++r) tmax[r] = fmaxf(tmax[r], __shfl_xor(tmax[r], m));
    float corr[4], psum[4];
#pragma unroll
    for (int r = 0; r < 4; ++r) {
      float mnew = fmaxf(m_run[r], tmax[r]);
      corr[r] = __expf(m_run[r] - mnew);
      m_run[r] = mnew;
      l_run[r] *= corr[r];
      psum[r] = 0.f;
    }
#pragma unroll
    for (int nt = 0; nt < 4; ++nt)
#pragma unroll
      for (int r = 0; r < 4; ++r) {
        float e = __expf(p[nt][r] - m_run[r]);
        p[nt][r] = e;
        psum[r] += e;
      }
#pragma unroll
    for (int m = 1; m < 16; m <<= 1)
#pragma unroll
      for (int r = 0; r < 4; ++r) psum[r] += __shfl_xor(psum[r], m);
#pragma unroll
    for (int r = 0; r < 4; ++r) l_run[r] += psum[r];
#pragma unroll
    for (int dt = 0; dt < 8; ++dt)
#pragma unroll
      for (int r = 0; r < 4; ++r) o_acc[dt][r] *= corr[r];

    // P -> per-wave LDS (A-operand layout source)
#pragma unroll
    for (int nt = 0; nt < 4; ++nt)
#pragma unroll
      for (int r = 0; r < 4; ++r)
        P_lds[wv][(l4 * 4 + r) * 72 + nt * 16 + l15] = f2b(p[nt][r]);

    // PV: O += P(16x64) * V(64x128)
#pragma unroll
    for (int kc = 0; kc < 2; ++kc) {
      bf16x8 pa = *(const bf16x8*)((const char*)&P_lds[wv][0] + l15 * 144 + kc * 64 + l4 * 16);
      int keygrp = kc * 4 + l4;
#pragma unroll
      for (int dt = 0; dt < 8; ++dt) {
        int d = dt * 16 + l15;
        int msk = (d & 7) ^ ((d >> 3) & 7);
        bf16x8 vb = *(const bf16x8*)&Vt_lds[d * 64 + ((keygrp ^ msk) << 3)];
        o_acc[dt] = __builtin_amdgcn_mfma_f32_16x16x32_bf16(pa, vb, o_acc[dt], 0, 0, 0);
      }
    }
  }
  float inv_l[4];
#pragma unroll
  for (int r = 0; r < 4; ++r) inv_l[r] = 1.0f / l_run[r];
#pragma unroll
  for (int dt = 0; dt < 8; ++dt)
#pragma unroll
    for (int r = 0; r < 4; ++r)
      o_bf[(size_t)(crow + r) * (NH * HD) + h * HD + dt * 16 + l15] = f2b(o_acc[dt][r] * inv_l[r]);
}

extern "C" void kernel_launch(void* const* d_in, const int* in_sizes, int n_in,
                              void* d_out, int out_size, void* d_ws, size_t ws_size,
                              hipStream_t stream) {
  const float* x    = (const float*)d_in[0];
  const float* Wq   = (const float*)d_in[1];
  const float* Wk   = (const float*)d_in[2];
  const float* Wv   = (const float*)d_in[3];
  const float* Wo   = (const float*)d_in[4];
  const float* cost = (const float*)d_in[5];
  const float* sint = (const float*)d_in[6];
  float* out = (float*)d_out;
  char* ws = (char*)d_ws;

  unsigned short* xb     = (unsigned short*)(ws);                 // 16 MB
  unsigned short* wqkv_t = (unsigned short*)(ws + 16777216);      // 48 MB (6144x4096)
  unsigned short* wo_t   = (unsigned short*)(ws + 67108864);      // 32 MB (4096x4096)
  float*          qkv    = (float*)(ws + 100663296);              // 48 MB (2048x6144)
  unsigned short* q_int  = (unsigned short*)(ws + 150994944);     // 16 MB
  unsigned short* k_int  = (unsigned short*)(ws + 167772160);     // 4 MB
  unsigned short* v_bf   = (unsigned short*)(ws + 171966464);     // 4 MB
  float*          q_ds   = (float*)(ws + 176160768);              // 256 KB
  float*          k_ds   = (float*)(ws + 176422912);              // 64 KB
  unsigned short* o_bf   = (unsigned short*)(ws + 176488448);     // 16 MB

  k_cvt_x<<<(S_LEN * DMODEL / 4) / 256, 256, 0, stream>>>(x, xb);
  k_transpose<<<dim3(64, 64), 256, 0, stream>>>(Wq, wqkv_t, 4096, 4096);
  k_transpose<<<dim3(64, 16), 256, 0, stream>>>(Wk, wqkv_t + (size_t)4096 * 4096, 4096, 1024);
  k_transpose<<<dim3(64, 16), 256, 0, stream>>>(Wv, wqkv_t + (size_t)5120 * 4096, 4096, 1024);
  k_transpose<<<dim3(64, 64), 256, 0, stream>>>(Wo, wo_t, 4096, 4096);
  k_gemm_bt<<<dim3(16, 48), 256, 0, stream>>>(xb, wqkv_t, qkv, 2048, 6144, 4096);
  k_ropequant<<<dim3(2048, 12), 256, 0, stream>>>(qkv, cost, sint, q_int, q_ds, k_int, k_ds, v_bf);
  k_attn<<<dim3(32, 32), 256, 0, stream>>>(q_int, q_ds, k_int, k_ds, v_bf, o_bf);
  k_gemm_bt<<<dim3(16, 32), 256, 0, stream>>>(o_bf, wo_t, out, 2048, 4096, 4096);
}

// Round 3
// 434.185 us; speedup vs baseline: 1.2176x; 1.2176x over previous
//
#include <hip/hip_runtime.h>
#include <hip/hip_bf16.h>

#define S_LEN 2048
#define DMODEL 4096
#define NH 32
#define NKV 8
#define HD 128
#define NQKV 6144
#define ATT_SCALE 0.08838834764831845f  // 1/sqrt(128)

typedef __bf16 bf16x8 __attribute__((ext_vector_type(8)));
typedef float f32x4 __attribute__((ext_vector_type(4)));

// float -> bf16 bits, round-to-nearest-even
__device__ __forceinline__ unsigned short f2b(float f) {
  union { float f; unsigned u; } a; a.f = f;
  unsigned u = a.u;
  return (unsigned short)((u + 0x7FFFu + ((u >> 16) & 1u)) >> 16);
}

__device__ __forceinline__ void gl16(const unsigned short* g, unsigned short* l) {
  __builtin_amdgcn_global_load_lds(
      (const __attribute__((address_space(1))) unsigned int*)g,
      (__attribute__((address_space(3))) unsigned int*)l, 16, 0, 0);
}

// ---------------- x fp32 -> bf16 ----------------
__global__ __launch_bounds__(256) void k_cvt_x(const float* __restrict__ x,
                                               unsigned short* __restrict__ xb) {
  int i = blockIdx.x * 256 + threadIdx.x;
  float4 v = ((const float4*)x)[i];
  ushort4 o;
  o.x = f2b(v.x); o.y = f2b(v.y); o.z = f2b(v.z); o.w = f2b(v.w);
  ((ushort4*)xb)[i] = o;
}

// ------------- W (K,N) fp32 -> Wt (N,K) bf16 -------------
__global__ __launch_bounds__(256) void k_transpose(const float* __restrict__ W,
                                                   unsigned short* __restrict__ Wt,
                                                   int K, int N) {
  __shared__ float tile[64][65];
  int k0 = blockIdx.x * 64, n0 = blockIdx.y * 64;
  int tx = threadIdx.x & 31, ty = threadIdx.x >> 5;
#pragma unroll
  for (int i = 0; i < 8; ++i) {
    int k = ty + i * 8;
    const float* src = W + (size_t)(k0 + k) * N + n0;
    tile[k][tx] = src[tx];
    tile[k][tx + 32] = src[tx + 32];
  }
  __syncthreads();
#pragma unroll
  for (int i = 0; i < 8; ++i) {
    int n = ty + i * 8;
    unsigned short* dst = Wt + (size_t)(n0 + n) * K + k0;
    dst[tx] = f2b(tile[tx][n]);
    dst[tx + 32] = f2b(tile[tx + 32][n]);
  }
}

// ------------- V [S][NKV][HD] bf16 -> V^T [NKV][HD][S] bf16 -------------
__global__ __launch_bounds__(256) void k_vt(const unsigned short* __restrict__ v_bf,
                                            unsigned short* __restrict__ v_t) {
  __shared__ unsigned short tile[64][65];
  int s0 = blockIdx.x * 64, d0 = blockIdx.y * 64, kvh = blockIdx.z;
  int tx = threadIdx.x & 63, ty = threadIdx.x >> 6;
#pragma unroll
  for (int i = 0; i < 16; ++i) {
    int s = ty + i * 4;
    tile[s][tx] = v_bf[((size_t)(s0 + s) * NKV + kvh) * HD + d0 + tx];
  }
  __syncthreads();
#pragma unroll
  for (int i = 0; i < 16; ++i) {
    int d = ty + i * 4;
    v_t[((size_t)kvh * HD + d0 + d) * S_LEN + s0 + tx] = tile[tx][d];
  }
}

// ------------- GEMM: C(MxN) fp32 = A(MxK) bf16 * Bt(NxK) bf16 -------------
__global__ __launch_bounds__(256) void k_gemm_bt(const unsigned short* __restrict__ A,
                                                 const unsigned short* __restrict__ B,
                                                 float* __restrict__ C,
                                                 int M, int N, int K) {
  __shared__ __align__(16) unsigned short As[128 * 32];
  __shared__ __align__(16) unsigned short Bs[128 * 32];
  const int tid = threadIdx.x, wv = tid >> 6, l = tid & 63;
  const int m0 = blockIdx.x * 128, n0 = blockIdx.y * 128;
  const int wm = (wv >> 1) * 64, wn = (wv & 1) * 64;
  const int l15 = l & 15, l4 = l >> 4;
  f32x4 acc[4][4] = {};
  for (int k0 = 0; k0 < K; k0 += 32) {
    __syncthreads();
#pragma unroll
    for (int j = 0; j < 2; ++j) {
      int rbase = wv * 32 + j * 16;
      const unsigned short* ga = A + (size_t)(m0 + rbase + (l >> 2)) * K + k0 + (l & 3) * 8;
      gl16(ga, &As[rbase * 32]);
      const unsigned short* gb = B + (size_t)(n0 + rbase + (l >> 2)) * K + k0 + (l & 3) * 8;
      gl16(gb, &Bs[rbase * 32]);
    }
    __syncthreads();
    bf16x8 af[4], bfr[4];
#pragma unroll
    for (int i = 0; i < 4; ++i)
      af[i] = *(const bf16x8*)&As[(wm + i * 16 + l15) * 32 + l4 * 8];
#pragma unroll
    for (int i = 0; i < 4; ++i)
      bfr[i] = *(const bf16x8*)&Bs[(wn + i * 16 + l15) * 32 + l4 * 8];
#pragma unroll
    for (int i = 0; i < 4; ++i)
#pragma unroll
      for (int j = 0; j < 4; ++j)
        acc[i][j] = __builtin_amdgcn_mfma_f32_16x16x32_bf16(af[i], bfr[j], acc[i][j], 0, 0, 0);
  }
#pragma unroll
  for (int i = 0; i < 4; ++i)
#pragma unroll
    for (int j = 0; j < 4; ++j)
#pragma unroll
      for (int r = 0; r < 4; ++r) {
        int row = m0 + wm + i * 16 + l4 * 4 + r;
        int col = n0 + wn + j * 16 + l15;
        C[(size_t)row * N + col] = acc[i][j][r];
      }
}

// ------------- RoPE + int8 quantize (stored as bf16 ints) -------------
__global__ __launch_bounds__(256) void k_ropequant(const float* __restrict__ qkv,
                                                   const float* __restrict__ cost,
                                                   const float* __restrict__ sint,
                                                   unsigned short* __restrict__ q_int,
                                                   float* __restrict__ q_ds,
                                                   unsigned short* __restrict__ k_int,
                                                   float* __restrict__ k_ds,
                                                   unsigned short* __restrict__ v_bf) {
  int s = blockIdx.x;
  int wv = threadIdx.x >> 6, l = threadIdx.x & 63;
  int hh = blockIdx.y * 4 + wv;  // 0..47: [0,32) q, [32,40) k, [40,48) v
  const float* row = qkv + (size_t)s * NQKV;
  if (hh < NH + NKV) {
    int off = (hh < NH) ? hh * HD : DMODEL + (hh - NH) * HD;
    float t1 = row[off + l], t2 = row[off + 64 + l];
    float c1 = cost[s * HD + l],      sn1 = sint[s * HD + l];
    float c2 = cost[s * HD + 64 + l], sn2 = sint[s * HD + 64 + l];
    float o1 = t1 * c1 - t2 * sn1;
    float o2 = t2 * c2 + t1 * sn2;
    float amax = fmaxf(fabsf(o1), fabsf(o2));
#pragma unroll
    for (int m = 1; m < 64; m <<= 1) amax = fmaxf(amax, __shfl_xor(amax, m));
    amax = fmaxf(amax, 1e-5f);
    float scale = 127.0f / amax;
    float dscale = amax * (1.0f / 127.0f);
    float v1 = fminf(fmaxf(rintf(o1 * scale), -128.f), 127.f);
    float v2 = fminf(fmaxf(rintf(o2 * scale), -128.f), 127.f);
    if (hh < NH) {
      unsigned short* dst = q_int + ((size_t)s * NH + hh) * HD;
      dst[l] = f2b(v1); dst[l + 64] = f2b(v2);
      if (l == 0) q_ds[(size_t)s * NH + hh] = dscale;
    } else {
      int kh = hh - NH;
      unsigned short* dst = k_int + ((size_t)s * NKV + kh) * HD;
      dst[l] = f2b(v1); dst[l + 64] = f2b(v2);
      if (l == 0) k_ds[(size_t)s * NKV + kh] = dscale;
    }
  } else {
    int vh = hh - (NH + NKV);
    const float* src = row + DMODEL + NKV * HD + vh * HD;
    unsigned short* dst = v_bf + ((size_t)s * NKV + vh) * HD;
    dst[l] = f2b(src[l]);
    dst[l + 64] = f2b(src[l + 64]);
  }
}

// ------------- causal GQA flash attention, paired q-tiles, async dbuf staging -------------
// grid 512; block = q-tiles (31-bx) then (bx): 33 KV tiles each; 2 blocks/CU exactly.
__global__ __launch_bounds__(256) void k_attn(const unsigned short* __restrict__ q_int,
                                              const float* __restrict__ q_ds,
                                              const unsigned short* __restrict__ k_int,
                                              const float* __restrict__ k_ds,
                                              const unsigned short* __restrict__ v_t,
                                              unsigned short* __restrict__ o_bf) {
  // K image: byte key*256 + (d*2 ^ ((key&7)<<4))            (round-1-proven layout)
  // V image: byte d*128 + (key*2 ^ ((d&7)<<4))  from V^T     (row-read conflict-minimal)
  __shared__ __align__(16) unsigned short K_lds[2][8192];
  __shared__ __align__(16) unsigned short V_lds[2][8192];
  __shared__ __align__(16) unsigned short P_lds[4][16 * 72];

  const int bid = blockIdx.x;
  const int kvh = bid & 7;                      // kvh == XCD id under %8 round-robin
  const int h = kvh * 4 + ((bid >> 3) & 3);
  const int bx = bid >> 5;                      // 0..15
  const int tid = threadIdx.x, wv = tid >> 6, l = tid & 63;
  const int l15 = l & 15, l4 = l >> 4;

  auto stage = [&](int b, int kt) {
    const unsigned short* kB = k_int + (size_t)kt * 64 * (NKV * HD) + kvh * HD;
    const unsigned short* vB = v_t + (size_t)kvh * HD * S_LEN + (size_t)kt * 64;
#pragma unroll
    for (int j = 0; j < 4; ++j) {
      int wi = j * 4 + wv;
      int slot = wi * 64 + l;
      // K: linear dest slot -> inverse-swizzled source column
      int key = slot >> 4;
      int colb = ((slot & 15) * 16) ^ ((key & 7) << 4);
      gl16(kB + key * (NKV * HD) + (colb >> 1), &K_lds[b][wi * 512]);
      // V^T: dest row d (64 keys, 128 B), inverse-swizzled key column
      int d = slot >> 3;
      int ckb = ((slot & 7) * 16) ^ ((d & 7) << 4);
      gl16(vB + (size_t)d * S_LEN + (ckb >> 1), &V_lds[b][wi * 512]);
    }
  };

  for (int ph = 0; ph < 2; ++ph) {
    const int qt = ph ? bx : (31 - bx);
    const int q0 = qt * 64;
    const int qrow_lo = q0 + wv * 16;
    const int crow = qrow_lo + l4 * 4;

    bf16x8 qf[4];
    {
      const unsigned short* qp = q_int + ((size_t)(qrow_lo + l15) * NH + h) * HD + l4 * 8;
#pragma unroll
      for (int kd = 0; kd < 4; ++kd) qf[kd] = *(const bf16x8*)(qp + kd * 32);
    }
    float qsS[4];
#pragma unroll
    for (int r = 0; r < 4; ++r) qsS[r] = ATT_SCALE * q_ds[(size_t)(crow + r) * NH + h];

    float m_run[4], l_run[4];
    f32x4 o_acc[8] = {};
#pragma unroll
    for (int r = 0; r < 4; ++r) { m_run[r] = -3.0e38f; l_run[r] = 0.f; }

    const int nkt = qt + 1;
    stage(0, 0);
    __syncthreads();  // drains vmcnt: tile 0 staged

    for (int kt = 0; kt < nkt; ++kt) {
      const int cur = kt & 1;
      float ksd[4];
#pragma unroll
      for (int nt = 0; nt < 4; ++nt)
        ksd[nt] = k_ds[(size_t)(kt * 64 + nt * 16 + l15) * NKV + kvh];
      if (kt + 1 < nkt) stage(cur ^ 1, kt + 1);  // async prefetch into other buffer

      // ---- QK^T (exact int accumulate in fp32) ----
      f32x4 sacc[4] = {};
#pragma unroll
      for (int nt = 0; nt < 4; ++nt) {
        int key = nt * 16 + l15;
#pragma unroll
        for (int kd = 0; kd < 4; ++kd) {
          int byte = key * 256 + kd * 64 + l4 * 16;
          byte ^= (key & 7) << 4;
          bf16x8 kf = *(const bf16x8*)((const char*)&K_lds[cur][0] + byte);
          sacc[nt] = __builtin_amdgcn_mfma_f32_16x16x32_bf16(qf[kd], kf, sacc[nt], 0, 0, 0);
        }
      }

      // ---- scale + causal mask + online softmax ----
      float p[4][4];
      float tmax[4] = {-3.0e38f, -3.0e38f, -3.0e38f, -3.0e38f};
#pragma unroll
      for (int nt = 0; nt < 4; ++nt) {
        int keyg = kt * 64 + nt * 16 + l15;
#pragma unroll
        for (int r = 0; r < 4; ++r) {
          float sc = sacc[nt][r] * (qsS[r] * ksd[nt]);
          sc = (keyg <= crow + r) ? sc : -3.0e38f;
          p[nt][r] = sc;
          tmax[r] = fmaxf(tmax[r], sc);
        }
      }
#pragma unroll
      for (int m = 1; m < 16; m <<= 1)
#pragma unroll
        for (int r = 0; r < 4; ++r) tmax[r] = fmaxf(tmax[r], __shfl_xor(tmax[r], m));
      float corr[4], psum[4];
#pragma unroll
      for (int r = 0; r < 4; ++r) {
        float mnew = fmaxf(m_run[r], tmax[r]);
        corr[r] = __expf(m_run[r] - mnew);
        m_run[r] = mnew;
        l_run[r] *= corr[r];
        psum[r] = 0.f;
      }
#pragma unroll
      for (int nt = 0; nt < 4; ++nt)
#pragma unroll
        for (int r = 0; r < 4; ++r) {
          float e = __expf(p[nt][r] - m_run[r]);
          p[nt][r] = e;
          psum[r] += e;
        }
#pragma unroll
      for (int m = 1; m < 16; m <<= 1)
#pragma unroll
        for (int r = 0; r < 4; ++r) psum[r] += __shfl_xor(psum[r], m);
#pragma unroll
      for (int r = 0; r < 4; ++r) l_run[r] += psum[r];
#pragma unroll
      for (int dt = 0; dt < 8; ++dt)
#pragma unroll
        for (int r = 0; r < 4; ++r) o_acc[dt][r] *= corr[r];

      // ---- P -> per-wave LDS (round-1-proven path) ----
#pragma unroll
      for (int nt = 0; nt < 4; ++nt)
#pragma unroll
        for (int r = 0; r < 4; ++r)
          P_lds[wv][(l4 * 4 + r) * 72 + nt * 16 + l15] = f2b(p[nt][r]);

      bf16x8 pa[2];
#pragma unroll
      for (int kc = 0; kc < 2; ++kc)
        pa[kc] = *(const bf16x8*)((const char*)&P_lds[wv][0] + l15 * 144 + kc * 64 + l4 * 16);

      // ---- PV: O += P(16x64) * V(64x128), V rows from swizzled V^T image ----
#pragma unroll
      for (int dt = 0; dt < 8; ++dt) {
        int d = dt * 16 + l15;
        int swz = (d & 7) << 4;
#pragma unroll
        for (int kc = 0; kc < 2; ++kc) {
          int byte = d * 128 + ((kc * 64 + l4 * 16) ^ swz);
          bf16x8 vb = *(const bf16x8*)((const char*)&V_lds[cur][0] + byte);
          o_acc[dt] = __builtin_amdgcn_mfma_f32_16x16x32_bf16(pa[kc], vb, o_acc[dt], 0, 0, 0);
        }
      }
      __syncthreads();  // drains vmcnt: next tile staged; orders buffer reuse
    }

    float inv_l[4];
#pragma unroll
    for (int r = 0; r < 4; ++r) inv_l[r] = 1.0f / l_run[r];
#pragma unroll
    for (int dt = 0; dt < 8; ++dt)
#pragma unroll
      for (int r = 0; r < 4; ++r)
        o_bf[(size_t)(crow + r) * (NH * HD) + h * HD + dt * 16 + l15] = f2b(o_acc[dt][r] * inv_l[r]);
  }
}

extern "C" void kernel_launch(void* const* d_in, const int* in_sizes, int n_in,
                              void* d_out, int out_size, void* d_ws, size_t ws_size,
                              hipStream_t stream) {
  const float* x    = (const float*)d_in[0];
  const float* Wq   = (const float*)d_in[1];
  const float* Wk   = (const float*)d_in[2];
  const float* Wv   = (const float*)d_in[3];
  const float* Wo   = (const float*)d_in[4];
  const float* cost = (const float*)d_in[5];
  const float* sint = (const float*)d_in[6];
  float* out = (float*)d_out;
  char* ws = (char*)d_ws;

  unsigned short* xb     = (unsigned short*)(ws);                 // 16 MB (dead after gemm1)
  unsigned short* wqkv_t = (unsigned short*)(ws + 16777216);      // 48 MB (6144x4096)
  unsigned short* wo_t   = (unsigned short*)(ws + 67108864);      // 32 MB (4096x4096)
  float*          qkv    = (float*)(ws + 100663296);              // 48 MB (2048x6144)
  unsigned short* q_int  = (unsigned short*)(ws + 150994944);     // 16 MB
  unsigned short* k_int  = (unsigned short*)(ws + 167772160);     // 4 MB
  unsigned short* v_bf   = (unsigned short*)(ws + 171966464);     // 4 MB
  float*          q_ds   = (float*)(ws + 176160768);              // 256 KB
  float*          k_ds   = (float*)(ws + 176422912);              // 64 KB
  unsigned short* o_bf   = (unsigned short*)(ws + 176488448);     // 16 MB
  unsigned short* v_t    = (unsigned short*)(ws);                 // 4 MB, aliases dead xb

  k_cvt_x<<<(S_LEN * DMODEL / 4) / 256, 256, 0, stream>>>(x, xb);
  k_transpose<<<dim3(64, 64), 256, 0, stream>>>(Wq, wqkv_t, 4096, 4096);
  k_transpose<<<dim3(64, 16), 256, 0, stream>>>(Wk, wqkv_t + (size_t)4096 * 4096, 4096, 1024);
  k_transpose<<<dim3(64, 16), 256, 0, stream>>>(Wv, wqkv_t + (size_t)5120 * 4096, 4096, 1024);
  k_transpose<<<dim3(64, 64), 256, 0, stream>>>(Wo, wo_t, 4096, 4096);
  k_gemm_bt<<<dim3(16, 48), 256, 0, stream>>>(xb, wqkv_t, qkv, 2048, 6144, 4096);
  k_ropequant<<<dim3(2048, 12), 256, 0, stream>>>(qkv, cost, sint, q_int, q_ds, k_int, k_ds, v_bf);
  k_vt<<<dim3(32, 2, 8), 256, 0, stream>>>(v_bf, v_t);
  k_attn<<<dim3(512), 256, 0, stream>>>(q_int, q_ds, k_int, k_ds, v_t, o_bf);
  k_gemm_bt<<<dim3(16, 32), 256, 0, stream>>>(o_bf, wo_t, out, 2048, 4096, 4096);
}